// Round 7
// baseline (758.370 us; speedup 1.0000x reference)
//
#include <hip/hip_runtime.h>
#include <hip/hip_bf16.h>
#include <stdint.h>

// ---------- helpers ----------
__device__ __forceinline__ uint16_t f2bf(float f) {
    union { float f; uint32_t u; } c; c.f = f;
    uint32_t u = c.u;
    return (uint16_t)((u + 0x7FFFu + ((u >> 16) & 1u)) >> 16);  // RNE
}
__device__ __forceinline__ uint32_t pack2(float a, float b) {
    return (uint32_t)f2bf(a) | ((uint32_t)f2bf(b) << 16);
}

typedef __bf16 bf16x8 __attribute__((ext_vector_type(8)));
typedef float  f32x4  __attribute__((ext_vector_type(4)));

#define GLOAD_LDS16(g, l) __builtin_amdgcn_global_load_lds( \
    (const __attribute__((address_space(1))) void*)(g),     \
    (__attribute__((address_space(3))) void*)(l), 16, 0, 0)

#define FENCE() asm volatile("" ::: "memory")
#define SCHEDB() __builtin_amdgcn_sched_barrier(0)

// ---------- Kernel 1: LayerNorm, fp32 in -> bf16 out. One block per row. ----------
__global__ __launch_bounds__(256) void ln_kernel(
    const float* __restrict__ x, const float* __restrict__ gw,
    const float* __restrict__ gb, uint16_t* __restrict__ y, int D)
{
    const int t = threadIdx.x;
    const size_t row = blockIdx.x;
    const float4* xr = (const float4*)(x + row * (size_t)D);
    float4 v0 = xr[2 * t], v1 = xr[2 * t + 1];

    float s  = v0.x + v0.y + v0.z + v0.w + v1.x + v1.y + v1.z + v1.w;
    float ss = v0.x * v0.x + v0.y * v0.y + v0.z * v0.z + v0.w * v0.w
             + v1.x * v1.x + v1.y * v1.y + v1.z * v1.z + v1.w * v1.w;
#pragma unroll
    for (int off = 32; off > 0; off >>= 1) {
        s  += __shfl_down(s, off);
        ss += __shfl_down(ss, off);
    }
    __shared__ float red[10];
    const int wave = t >> 6, lane = t & 63;
    if (lane == 0) { red[wave] = s; red[4 + wave] = ss; }
    __syncthreads();
    if (t == 0) {
        float S  = red[0] + red[1] + red[2] + red[3];
        float SS = red[4] + red[5] + red[6] + red[7];
        float mu = S / (float)D;
        float var = SS / (float)D - mu * mu;
        red[8] = mu;
        red[9] = rsqrtf(var + 1e-5f);
    }
    __syncthreads();
    const float mu = red[8], rstd = red[9];

    const float4* wr = (const float4*)gw;
    const float4* br = (const float4*)gb;
    float4 w0 = wr[2 * t], w1 = wr[2 * t + 1];
    float4 b0 = br[2 * t], b1 = br[2 * t + 1];

    uint4 ov;
    ov.x = pack2((v0.x - mu) * rstd * w0.x + b0.x, (v0.y - mu) * rstd * w0.y + b0.y);
    ov.y = pack2((v0.z - mu) * rstd * w0.z + b0.z, (v0.w - mu) * rstd * w0.w + b0.w);
    ov.z = pack2((v1.x - mu) * rstd * w1.x + b1.x, (v1.y - mu) * rstd * w1.y + b1.y);
    ov.w = pack2((v1.z - mu) * rstd * w1.z + b1.z, (v1.w - mu) * rstd * w1.w + b1.w);
    ((uint4*)(y + row * (size_t)D))[t] = ov;
}

// ---------- Kernel 2: weights fp32 -> bf16, concat [Wq;Wk;Wv] ----------
__global__ __launch_bounds__(256) void wcvt_kernel(
    const float* __restrict__ wq, const float* __restrict__ wk,
    const float* __restrict__ wv, uint16_t* __restrict__ out)
{
    const size_t i = ((size_t)blockIdx.x * 256 + threadIdx.x) * 8;
    const int which = (int)(i >> 22);            // 2048*2048 = 2^22 per matrix
    const float* src = (which == 0) ? wq : (which == 1) ? wk : wv;
    const size_t off = i & ((1u << 22) - 1);
    float4 a = *(const float4*)(src + off);
    float4 b = *(const float4*)(src + off + 4);
    uint4 ov;
    ov.x = pack2(a.x, a.y);
    ov.y = pack2(a.z, a.w);
    ov.z = pack2(b.x, b.y);
    ov.w = pack2(b.z, b.w);
    *(uint4*)(out + i) = ov;
}

// ---------- Kernel 3: 256x256, BK=64, 8 waves, modulo-scheduled 4-phase ----------
// R6 model: 1 block/CU (128KiB LDS); per tile MFMA 2478cy + LDS 2304cy were
// SERIALIZED (measured 4900cy/tile). This version modulo-schedules: every
// MFMA cluster consumes operands ds_read 1-2 phases earlier; reads spread
// ~4-8/phase incl. cross-tile prefetch of Bf(t+1) @p2 and Q0/Q1(t+1) @p3.
// Visibility: vmcnt(4)+barrier @p1-end (B(t+1)), vmcnt(2)+barrier @p2-end
// (A(t+1)). One barrier per phase. Registers: acc128 + X/Y 32 + BfA/B 64.
// LDS: A[slot][half] 4x16KB at 0, B[slot][half] 4x16KB at 65536.

#define STAGE_A(H, KT, SL) do {                                               \
    const uint16_t* g_ = gA + (size_t)((H) * 128) * K + (KT) * 64;            \
    char* l_ = (char*)lds + (((SL) * 2 + (H)) * 16384) + t * 16;              \
    GLOAD_LDS16(g_, l_);                                                      \
    GLOAD_LDS16(g_ + (size_t)64 * K, l_ + 8192);                              \
} while (0)

#define STAGE_B(H, KT, SL) do {                                               \
    const uint16_t* g_ = gB + (size_t)((H) * 128) * K + (KT) * 64;            \
    char* l_ = (char*)lds + 65536 + (((SL) * 2 + (H)) * 16384) + t * 16;      \
    GLOAD_LDS16(g_, l_);                                                      \
    GLOAD_LDS16(g_ + (size_t)64 * K, l_ + 8192);                              \
} while (0)

// read A quad P (m-frags 2P,2P+1 x 2 k-slices) from ABASE into buf
#define DS_READ_Q(buf, P, ABASE)                                              \
    _Pragma("unroll") for (int m_ = 0; m_ < 2; ++m_)                          \
      _Pragma("unroll") for (int s_ = 0; s_ < 2; ++s_)                        \
        buf[m_][s_] = *(const bf16x8*)((const char*)lds + (ABASE)             \
                                       + (aoff ^ (s_ << 6))                   \
                                       + (2 * (P) + m_) * 2048);

#define DS_READ_B(BF, BBASE)                                                  \
    _Pragma("unroll") for (int j_ = 0; j_ < 4; ++j_)                          \
      _Pragma("unroll") for (int s_ = 0; s_ < 2; ++s_)                        \
        BF[j_][s_] = *(const bf16x8*)((const char*)lds + (BBASE)              \
                                      + (boff ^ (s_ << 6)) + j_ * 2048);

#define MFMA16(P, buf, BF)                                                    \
    __builtin_amdgcn_s_setprio(1);                                            \
    _Pragma("unroll") for (int s_ = 0; s_ < 2; ++s_)                          \
      _Pragma("unroll") for (int m_ = 0; m_ < 2; ++m_)                        \
        _Pragma("unroll") for (int j_ = 0; j_ < 4; ++j_)                      \
          acc[2 * (P) + m_][j_] = __builtin_amdgcn_mfma_f32_16x16x32_bf16(    \
              buf[m_][s_], BF[j_][s_], acc[2 * (P) + m_][j_], 0, 0, 0);       \
    __builtin_amdgcn_s_setprio(0);

// Entering tile t: Xq=Q0(t), Yq=Q1(t), BFC=Bf(t); 4 outstanding DMAs = B(t+1).
// p0: MFMA Q0; read Q2(t)->Xq after (WAR ok, dataflow keeps order)
// p1: MFMA Q1; read Q3(t)->Yq; vmcnt(4) [B(t+1) retired] + barrier
// p2: read Bf(t+1)->BFN (pinned before MFMA); MFMA Q2; vmcnt(2) [A(t+1)] + bar
// p3: read Q0(t+1)->Xq (pinned); MFMA Q3; read Q1(t+1)->Yq
#define KTILE(SLOT, KT, BFC, BFN, SA, SB, PFN, VM1, VM2)                      \
  {                                                                           \
    const int ab_  = ((SLOT) * 2 + wr) * 16384;                               \
    const int abn_ = (((SLOT) ^ 1) * 2 + wr) * 16384;                         \
    const int bbn_ = 65536 + (((SLOT) ^ 1) * 2 + (wc >> 1)) * 16384;          \
    /* p0 */                                                                  \
    if (SA) STAGE_A(0, (KT) + 1, (SLOT) ^ 1);                                 \
    MFMA16(0, Xq, BFC);                                                       \
    DS_READ_Q(Xq, 2, ab_);                                                    \
    FENCE(); __builtin_amdgcn_s_barrier(); FENCE();                           \
    /* p1 */                                                                  \
    if (SA) STAGE_A(1, (KT) + 1, (SLOT) ^ 1);                                 \
    MFMA16(1, Yq, BFC);                                                       \
    DS_READ_Q(Yq, 3, ab_);                                                    \
    VM1 FENCE(); __builtin_amdgcn_s_barrier(); FENCE();                       \
    /* p2 */                                                                  \
    if (PFN) { DS_READ_B(BFN, bbn_); }                                        \
    if (SB) STAGE_B(0, (KT) + 2, (SLOT));                                     \
    SCHEDB();                                                                 \
    MFMA16(2, Xq, BFC);                                                       \
    VM2 FENCE(); __builtin_amdgcn_s_barrier(); FENCE();                       \
    /* p3 */                                                                  \
    if (PFN) { DS_READ_Q(Xq, 0, abn_); }                                      \
    if (SB) STAGE_B(1, (KT) + 2, (SLOT));                                     \
    SCHEDB();                                                                 \
    MFMA16(3, Yq, BFC);                                                       \
    if (PFN) { DS_READ_Q(Yq, 1, abn_); }                                      \
    FENCE(); __builtin_amdgcn_s_barrier(); FENCE();                           \
  }

#define VM4 asm volatile("s_waitcnt vmcnt(4)" ::: "memory");
#define VM2W asm volatile("s_waitcnt vmcnt(2)" ::: "memory");
#define VM0 asm volatile("s_waitcnt vmcnt(0)" ::: "memory");

__global__ __launch_bounds__(512, 2) void qkv_gemm256(
    const uint16_t* __restrict__ A, const uint16_t* __restrict__ W,
    const float* __restrict__ Bq, const float* __restrict__ Bk,
    const float* __restrict__ Bv, float* __restrict__ C,
    int M, int N, int K)
{
    (void)M;
    extern __shared__ uint16_t lds[];
    const int t = threadIdx.x;
    const int lane = t & 63, wid = t >> 6;
    const int wr = wid >> 2, wc = wid & 3;          // 2 x 4 wave grid
    const int fr = lane & 15;
    const int fq2 = (lane >> 4) * 16;               // k-frag byte offset

    // T1: XCD swizzle + within-XCD band reorder (R5: FETCH 320->147MB).
    const int nbt = N >> 8;                         // 24 col-tiles
    const int nwg = gridDim.x;
    int mb, nb;
    if ((nwg & 7) == 0) {
        const int cpx = nwg >> 3;                   // 96 tiles per XCD
        const int xcd = blockIdx.x & 7, ti = blockIdx.x >> 3;
        if (cpx % nbt == 0 && (nbt & 7) == 0) {
            const int band = ti >> 5, r = ti & 31;
            mb = xcd * (cpx / nbt) + (r >> 3);
            nb = (band << 3) + (r & 7);
        } else {
            const int swz = xcd * cpx + ti;
            mb = swz / nbt; nb = swz % nbt;
        }
    } else {
        mb = blockIdx.x / nbt; nb = blockIdx.x % nbt;
    }

    // read-side swizzle q -> q ^ ((row&7)<<4)  (R5: 0 bank conflicts)
    const int kbase = fq2 ^ ((fr & 7) << 4);
    const int aoff = fr * 128 + kbase;
    const int boff = ((wc & 1) * 64 + fr) * 128 + kbase;

    // write-side pre-swizzled global source (same involution)
    const int srow = t >> 3;
    const int scol = (((t & 7) ^ ((t >> 3) & 7)) << 3);
    const uint16_t* gA = A + (size_t)(mb * 256 + srow) * K + scol;
    const uint16_t* gB = W + (size_t)(nb * 256 + srow) * K + scol;

    f32x4 acc[8][4] = {};
    bf16x8 Xq[2][2], Yq[2][2], BfA[4][2], BfB[4][2];
    const int NT = K >> 6;                          // 32 K-tiles

    // prologue: B(0),A(0)->slot0; B(1)->slot1; retire B0/A0, keep B1 in flight
    STAGE_B(0, 0, 0); STAGE_B(1, 0, 0);
    STAGE_A(0, 0, 0); STAGE_A(1, 0, 0);
    STAGE_B(0, 1, 1); STAGE_B(1, 1, 1);
    VM4
    __builtin_amdgcn_s_barrier();
    FENCE();
    // initial reads: Bf(0)->BfA, Q0(0)->Xq, Q1(0)->Yq  (slot0)
    {
        const int ab_ = wr * 16384;
        const int bb_ = 65536 + (wc >> 1) * 16384;
        DS_READ_B(BfA, bb_);
        DS_READ_Q(Xq, 0, ab_);
        DS_READ_Q(Yq, 1, ab_);
    }
    FENCE();

#pragma unroll 1
    for (int i = 0; i < (NT >> 1) - 1; ++i) {       // tiles 0..29
        const int k0 = i << 1;
        KTILE(0, k0,     BfA, BfB, 1, 1, 1, VM4, VM2W)
        KTILE(1, k0 + 1, BfB, BfA, 1, 1, 1, VM4, VM2W)
    }
    // tile 30: stage A(31) only, drain A(31) fully at p2-end
    KTILE(0, NT - 2, BfA, BfB, 1, 0, 1, VM4, VM0)
    // tile 31: compute-only (Q2/Q3 of tile 31 still read in-phase via p0/p1)
    KTILE(1, NT - 1, BfB, BfA, 0, 0, 0, , )

    // epilogue: C/D layout row=(lane>>4)*4+reg, col=lane&15. fp32 stores + bias.
    const int r0 = mb * 256 + wr * 128 + (lane >> 4) * 4;
    const int c0 = nb * 256 + wc * 64 + fr;
    const float* bp = (nb < 8) ? Bq : (nb < 16) ? Bk : Bv;
    const int cb = (nb & 7) * 256 + wc * 64 + fr;
    float bj[4];
#pragma unroll
    for (int j = 0; j < 4; ++j) bj[j] = bp[cb + j * 16];
#pragma unroll
    for (int i = 0; i < 8; ++i)
#pragma unroll
        for (int j = 0; j < 4; ++j)
#pragma unroll
            for (int r = 0; r < 4; ++r)
                C[(size_t)(r0 + i * 16 + r) * N + c0 + j * 16] = acc[i][j][r] + bj[j];
}

extern "C" void kernel_launch(void* const* d_in, const int* in_sizes, int n_in,
                              void* d_out, int out_size, void* d_ws, size_t ws_size,
                              hipStream_t stream) {
    const float* x  = (const float*)d_in[0];
    const float* nw = (const float*)d_in[1];
    const float* nb = (const float*)d_in[2];
    const float* wq = (const float*)d_in[3];
    const float* bq = (const float*)d_in[4];
    const float* wk = (const float*)d_in[5];
    const float* bk = (const float*)d_in[6];
    const float* wv = (const float*)d_in[7];
    const float* bv = (const float*)d_in[8];

    const int D = in_sizes[1];        // 2048
    const int M = in_sizes[0] / D;    // 8192 (B*S)
    const int N = 3 * D;              // 6144

    static bool attr_done = false;
    if (!attr_done) {
        hipFuncSetAttribute((const void*)qkv_gemm256,
                            hipFuncAttributeMaxDynamicSharedMemorySize, 131072);
        attr_done = true;
    }

    // ws layout: [normed bf16: M*D] [Wcat bf16: N*D]
    uint16_t* normed = (uint16_t*)d_ws;
    uint16_t* wcat   = normed + (size_t)M * D;

    ln_kernel<<<M, 256, 0, stream>>>(x, nw, nb, normed, D);
    wcvt_kernel<<<((size_t)N * D) / (256 * 8), 256, 0, stream>>>(wq, wk, wv, wcat);
    const int grid = (M / 256) * (N / 256);          // 768, %8==0
    qkv_gemm256<<<grid, 512, 131072, stream>>>(normed, wcat, bq, bk, bv,
                                               (float*)d_out, M, N, D);
}

// Round 8
// 444.443 us; speedup vs baseline: 1.7063x; 1.7063x over previous
//
#include <hip/hip_runtime.h>
#include <hip/hip_bf16.h>
#include <stdint.h>

// ---------- helpers ----------
__device__ __forceinline__ uint16_t f2bf(float f) {
    union { float f; uint32_t u; } c; c.f = f;
    uint32_t u = c.u;
    return (uint16_t)((u + 0x7FFFu + ((u >> 16) & 1u)) >> 16);  // RNE
}
__device__ __forceinline__ uint32_t pack2(float a, float b) {
    return (uint32_t)f2bf(a) | ((uint32_t)f2bf(b) << 16);
}

typedef __bf16 bf16x8 __attribute__((ext_vector_type(8)));
typedef float  f32x4  __attribute__((ext_vector_type(4)));

#define GLOAD_LDS16(g, l) __builtin_amdgcn_global_load_lds( \
    (const __attribute__((address_space(1))) void*)(g),     \
    (__attribute__((address_space(3))) void*)(l), 16, 0, 0)

#define FENCE() asm volatile("" ::: "memory")
#define SCHEDB() __builtin_amdgcn_sched_barrier(0)

// ---------- Kernel 1: LayerNorm, fp32 in -> bf16 out. One block per row. ----------
__global__ __launch_bounds__(256) void ln_kernel(
    const float* __restrict__ x, const float* __restrict__ gw,
    const float* __restrict__ gb, uint16_t* __restrict__ y, int D)
{
    const int t = threadIdx.x;
    const size_t row = blockIdx.x;
    const float4* xr = (const float4*)(x + row * (size_t)D);
    float4 v0 = xr[2 * t], v1 = xr[2 * t + 1];

    float s  = v0.x + v0.y + v0.z + v0.w + v1.x + v1.y + v1.z + v1.w;
    float ss = v0.x * v0.x + v0.y * v0.y + v0.z * v0.z + v0.w * v0.w
             + v1.x * v1.x + v1.y * v1.y + v1.z * v1.z + v1.w * v1.w;
#pragma unroll
    for (int off = 32; off > 0; off >>= 1) {
        s  += __shfl_down(s, off);
        ss += __shfl_down(ss, off);
    }
    __shared__ float red[10];
    const int wave = t >> 6, lane = t & 63;
    if (lane == 0) { red[wave] = s; red[4 + wave] = ss; }
    __syncthreads();
    if (t == 0) {
        float S  = red[0] + red[1] + red[2] + red[3];
        float SS = red[4] + red[5] + red[6] + red[7];
        float mu = S / (float)D;
        float var = SS / (float)D - mu * mu;
        red[8] = mu;
        red[9] = rsqrtf(var + 1e-5f);
    }
    __syncthreads();
    const float mu = red[8], rstd = red[9];

    const float4* wr = (const float4*)gw;
    const float4* br = (const float4*)gb;
    float4 w0 = wr[2 * t], w1 = wr[2 * t + 1];
    float4 b0 = br[2 * t], b1 = br[2 * t + 1];

    uint4 ov;
    ov.x = pack2((v0.x - mu) * rstd * w0.x + b0.x, (v0.y - mu) * rstd * w0.y + b0.y);
    ov.y = pack2((v0.z - mu) * rstd * w0.z + b0.z, (v0.w - mu) * rstd * w0.w + b0.w);
    ov.z = pack2((v1.x - mu) * rstd * w1.x + b1.x, (v1.y - mu) * rstd * w1.y + b1.y);
    ov.w = pack2((v1.z - mu) * rstd * w1.z + b1.z, (v1.w - mu) * rstd * w1.w + b1.w);
    ((uint4*)(y + row * (size_t)D))[t] = ov;
}

// ---------- Kernel 2: weights fp32 -> bf16, concat [Wq;Wk;Wv] ----------
__global__ __launch_bounds__(256) void wcvt_kernel(
    const float* __restrict__ wq, const float* __restrict__ wk,
    const float* __restrict__ wv, uint16_t* __restrict__ out)
{
    const size_t i = ((size_t)blockIdx.x * 256 + threadIdx.x) * 8;
    const int which = (int)(i >> 22);            // 2048*2048 = 2^22 per matrix
    const float* src = (which == 0) ? wq : (which == 1) ? wk : wv;
    const size_t off = i & ((1u << 22) - 1);
    float4 a = *(const float4*)(src + off);
    float4 b = *(const float4*)(src + off + 4);
    uint4 ov;
    ov.x = pack2(a.x, a.y);
    ov.y = pack2(a.z, a.w);
    ov.z = pack2(b.x, b.y);
    ov.w = pack2(b.z, b.w);
    *(uint4*)(out + i) = ov;
}

// ---------- Kernel 3: 256x256, BK=64, 8 waves, modulo-scheduled, no spill ------
// R7 lesson: acc128+BfA32+BfB32+Xq16+Yq16+temps > 256 VGPR cap -> 1GB scratch
// spill (WRITE_SIZE 197MB->1.21GB). This version keeps the cross-phase A-quad
// pipeline (Xq/Yq) but reads the SINGLE Bf at p0 of each tile via normal
// dataflow (true dep, ~200cy once per tile). Live regs ~228 < 256.
// Stage/vmcnt schedule identical to R7 (re-audited for in-tile Bf read):
// tile t: STAGE_A(t+1)@p0/p1, STAGE_B(t+2)@p2/p3; vmcnt(4)@p1 retires B(t+1)
// (read at t+1 p0); vmcnt(2)@p2 retires A(t+1) (read at t p3 prefetch).
// T1 XCD+band swizzle, T2 3-bit XOR (0 conflicts), T5 setprio.
// LDS: A[slot][half] 4x16KB at 0, B[slot][half] 4x16KB at 65536.

#define STAGE_A(H, KT, SL) do {                                               \
    const uint16_t* g_ = gA + (size_t)((H) * 128) * K + (KT) * 64;            \
    char* l_ = (char*)lds + (((SL) * 2 + (H)) * 16384) + t * 16;              \
    GLOAD_LDS16(g_, l_);                                                      \
    GLOAD_LDS16(g_ + (size_t)64 * K, l_ + 8192);                              \
} while (0)

#define STAGE_B(H, KT, SL) do {                                               \
    const uint16_t* g_ = gB + (size_t)((H) * 128) * K + (KT) * 64;            \
    char* l_ = (char*)lds + 65536 + (((SL) * 2 + (H)) * 16384) + t * 16;      \
    GLOAD_LDS16(g_, l_);                                                      \
    GLOAD_LDS16(g_ + (size_t)64 * K, l_ + 8192);                              \
} while (0)

// read A quad P (m-frags 2P,2P+1 x 2 k-slices) from ABASE into buf
#define DS_READ_Q(buf, P, ABASE)                                              \
    _Pragma("unroll") for (int m_ = 0; m_ < 2; ++m_)                          \
      _Pragma("unroll") for (int s_ = 0; s_ < 2; ++s_)                        \
        buf[m_][s_] = *(const bf16x8*)((const char*)lds + (ABASE)             \
                                       + (aoff ^ (s_ << 6))                   \
                                       + (2 * (P) + m_) * 2048);

#define DS_READ_B(BF, BBASE)                                                  \
    _Pragma("unroll") for (int j_ = 0; j_ < 4; ++j_)                          \
      _Pragma("unroll") for (int s_ = 0; s_ < 2; ++s_)                        \
        BF[j_][s_] = *(const bf16x8*)((const char*)lds + (BBASE)              \
                                      + (boff ^ (s_ << 6)) + j_ * 2048);

#define MFMA16(P, buf)                                                        \
    __builtin_amdgcn_s_setprio(1);                                            \
    _Pragma("unroll") for (int s_ = 0; s_ < 2; ++s_)                          \
      _Pragma("unroll") for (int m_ = 0; m_ < 2; ++m_)                        \
        _Pragma("unroll") for (int j_ = 0; j_ < 4; ++j_)                      \
          acc[2 * (P) + m_][j_] = __builtin_amdgcn_mfma_f32_16x16x32_bf16(    \
              buf[m_][s_], Bf[j_][s_], acc[2 * (P) + m_][j_], 0, 0, 0);       \
    __builtin_amdgcn_s_setprio(0);

// Entering tile t: Xq=Q0(t), Yq=Q1(t) (read at t-1 p3); B(t) retired+barriered.
// p0: read Bf(t) (true dep feeds MFMA); MFMA Q0; refill Xq<-Q2(t)
// p1: MFMA Q1; refill Yq<-Q3(t); vmcnt(4) [retire B(t+1)] + barrier
// p2: MFMA Q2; vmcnt(2) [retire A(t+1)] + barrier
// p3: prefetch Xq<-Q0(t+1) (pinned); MFMA Q3; prefetch Yq<-Q1(t+1)
#define KTILE(SLOT, KT, SA, SB, PFN, VM1, VM2)                                \
  {                                                                           \
    const int ab_  = ((SLOT) * 2 + wr) * 16384;                               \
    const int abn_ = (((SLOT) ^ 1) * 2 + wr) * 16384;                         \
    const int bb_  = 65536 + ((SLOT) * 2 + (wc >> 1)) * 16384;                \
    bf16x8 Bf[4][2];                                                          \
    /* p0 */                                                                  \
    if (SA) STAGE_A(0, (KT) + 1, (SLOT) ^ 1);                                 \
    DS_READ_B(Bf, bb_);                                                       \
    MFMA16(0, Xq);                                                            \
    DS_READ_Q(Xq, 2, ab_);                                                    \
    FENCE(); __builtin_amdgcn_s_barrier(); FENCE();                           \
    /* p1 */                                                                  \
    if (SA) STAGE_A(1, (KT) + 1, (SLOT) ^ 1);                                 \
    MFMA16(1, Yq);                                                            \
    DS_READ_Q(Yq, 3, ab_);                                                    \
    VM1 FENCE(); __builtin_amdgcn_s_barrier(); FENCE();                       \
    /* p2 */                                                                  \
    if (SB) STAGE_B(0, (KT) + 2, (SLOT));                                     \
    MFMA16(2, Xq);                                                            \
    VM2 FENCE(); __builtin_amdgcn_s_barrier(); FENCE();                       \
    /* p3 */                                                                  \
    if (PFN) { DS_READ_Q(Xq, 0, abn_); }                                      \
    if (SB) STAGE_B(1, (KT) + 2, (SLOT));                                     \
    SCHEDB();                                                                 \
    MFMA16(3, Yq);                                                            \
    if (PFN) { DS_READ_Q(Yq, 1, abn_); }                                      \
    FENCE(); __builtin_amdgcn_s_barrier(); FENCE();                           \
  }

#define VM4 asm volatile("s_waitcnt vmcnt(4)" ::: "memory");
#define VM2W asm volatile("s_waitcnt vmcnt(2)" ::: "memory");
#define VM0 asm volatile("s_waitcnt vmcnt(0)" ::: "memory");

__global__ __launch_bounds__(512, 2) void qkv_gemm256(
    const uint16_t* __restrict__ A, const uint16_t* __restrict__ W,
    const float* __restrict__ Bq, const float* __restrict__ Bk,
    const float* __restrict__ Bv, float* __restrict__ C,
    int M, int N, int K)
{
    (void)M;
    extern __shared__ uint16_t lds[];
    const int t = threadIdx.x;
    const int lane = t & 63, wid = t >> 6;
    const int wr = wid >> 2, wc = wid & 3;          // 2 x 4 wave grid
    const int fr = lane & 15;
    const int fq2 = (lane >> 4) * 16;               // k-frag byte offset

    // T1: XCD swizzle + within-XCD band reorder (R5: FETCH 320->147MB).
    const int nbt = N >> 8;                         // 24 col-tiles
    const int nwg = gridDim.x;
    int mb, nb;
    if ((nwg & 7) == 0) {
        const int cpx = nwg >> 3;                   // 96 tiles per XCD
        const int xcd = blockIdx.x & 7, ti = blockIdx.x >> 3;
        if (cpx % nbt == 0 && (nbt & 7) == 0) {
            const int band = ti >> 5, r = ti & 31;
            mb = xcd * (cpx / nbt) + (r >> 3);
            nb = (band << 3) + (r & 7);
        } else {
            const int swz = xcd * cpx + ti;
            mb = swz / nbt; nb = swz % nbt;
        }
    } else {
        mb = blockIdx.x / nbt; nb = blockIdx.x % nbt;
    }

    // read-side swizzle q -> q ^ ((row&7)<<4)  (R5: 0 bank conflicts)
    const int kbase = fq2 ^ ((fr & 7) << 4);
    const int aoff = fr * 128 + kbase;
    const int boff = ((wc & 1) * 64 + fr) * 128 + kbase;

    // write-side pre-swizzled global source (same involution)
    const int srow = t >> 3;
    const int scol = (((t & 7) ^ ((t >> 3) & 7)) << 3);
    const uint16_t* gA = A + (size_t)(mb * 256 + srow) * K + scol;
    const uint16_t* gB = W + (size_t)(nb * 256 + srow) * K + scol;

    f32x4 acc[8][4] = {};
    bf16x8 Xq[2][2], Yq[2][2];
    const int NT = K >> 6;                          // 32 K-tiles

    // prologue: B(0),A(0)->slot0; B(1)->slot1; retire B0/A0, keep B1 in flight
    STAGE_B(0, 0, 0); STAGE_B(1, 0, 0);
    STAGE_A(0, 0, 0); STAGE_A(1, 0, 0);
    STAGE_B(0, 1, 1); STAGE_B(1, 1, 1);
    VM4
    __builtin_amdgcn_s_barrier();
    FENCE();
    // initial reads: Q0(0)->Xq, Q1(0)->Yq  (slot0)
    {
        const int ab_ = wr * 16384;
        DS_READ_Q(Xq, 0, ab_);
        DS_READ_Q(Yq, 1, ab_);
    }
    FENCE();

#pragma unroll 1
    for (int i = 0; i < (NT >> 1) - 1; ++i) {       // tiles 0..29
        const int k0 = i << 1;
        KTILE(0, k0,     1, 1, 1, VM4, VM2W)
        KTILE(1, k0 + 1, 1, 1, 1, VM4, VM2W)
    }
    // tile 30: stage A(31) only, drain A(31) fully at p2-end
    KTILE(0, NT - 2, 1, 0, 1, VM4, VM0)
    // tile 31: compute-only (Q2/Q3 still refilled in-phase at p0/p1)
    KTILE(1, NT - 1, 0, 0, 0, , )

    // epilogue: C/D layout row=(lane>>4)*4+reg, col=lane&15. fp32 stores + bias.
    const int r0 = mb * 256 + wr * 128 + (lane >> 4) * 4;
    const int c0 = nb * 256 + wc * 64 + fr;
    const float* bp = (nb < 8) ? Bq : (nb < 16) ? Bk : Bv;
    const int cb = (nb & 7) * 256 + wc * 64 + fr;
    float bj[4];
#pragma unroll
    for (int j = 0; j < 4; ++j) bj[j] = bp[cb + j * 16];
#pragma unroll
    for (int i = 0; i < 8; ++i)
#pragma unroll
        for (int j = 0; j < 4; ++j)
#pragma unroll
            for (int r = 0; r < 4; ++r)
                C[(size_t)(r0 + i * 16 + r) * N + c0 + j * 16] = acc[i][j][r] + bj[j];
}

extern "C" void kernel_launch(void* const* d_in, const int* in_sizes, int n_in,
                              void* d_out, int out_size, void* d_ws, size_t ws_size,
                              hipStream_t stream) {
    const float* x  = (const float*)d_in[0];
    const float* nw = (const float*)d_in[1];
    const float* nb = (const float*)d_in[2];
    const float* wq = (const float*)d_in[3];
    const float* bq = (const float*)d_in[4];
    const float* wk = (const float*)d_in[5];
    const float* bk = (const float*)d_in[6];
    const float* wv = (const float*)d_in[7];
    const float* bv = (const float*)d_in[8];

    const int D = in_sizes[1];        // 2048
    const int M = in_sizes[0] / D;    // 8192 (B*S)
    const int N = 3 * D;              // 6144

    static bool attr_done = false;
    if (!attr_done) {
        hipFuncSetAttribute((const void*)qkv_gemm256,
                            hipFuncAttributeMaxDynamicSharedMemorySize, 131072);
        attr_done = true;
    }

    // ws layout: [normed bf16: M*D] [Wcat bf16: N*D]
    uint16_t* normed = (uint16_t*)d_ws;
    uint16_t* wcat   = normed + (size_t)M * D;

    ln_kernel<<<M, 256, 0, stream>>>(x, nw, nb, normed, D);
    wcvt_kernel<<<((size_t)N * D) / (256 * 8), 256, 0, stream>>>(wq, wk, wv, wcat);
    const int grid = (M / 256) * (N / 256);          // 768, %8==0
    qkv_gemm256<<<grid, 512, 131072, stream>>>(normed, wcat, bq, bk, bv,
                                               (float*)d_out, M, N, D);
}